// Round 2
// baseline (770.888 us; speedup 1.0000x reference)
//
#include <hip/hip_runtime.h>
#include <hip/hip_bf16.h>

// Shapes (fixed by reference): B=32, T=2048, H=1024, U=1024.
// out = [context (32*1024)][attention_weights (32*2048)]  (fp32)
// V_b is a uniform score shift -> cancels in softmax -> unused.

#define B_DIM 32
#define T_DIM 2048
#define H_DIM 1024
#define U_DIM 1024

typedef __bf16 bf16x8 __attribute__((ext_vector_type(8)));
typedef float f32x4 __attribute__((ext_vector_type(4)));

__device__ __forceinline__ unsigned int f2bf(float f) {
    unsigned int u = __float_as_uint(f);
    return (u + 0x7FFFu + ((u >> 16) & 1u)) >> 16;   // RNE
}

__device__ __forceinline__ float fast_tanh(float x) {
    x = fminf(9.f, fmaxf(-9.f, x));
    float e = __expf(2.f * x);
    return 1.f - 2.f * __frcp_rn(e + 1.f);
}

// ---------- pass 0a: Wv (first H cols of W_w rows) -> bf16, natural [u][k] ----------
__global__ void prep_wv_kernel(const float* __restrict__ W_w,
                               unsigned short* __restrict__ wv) {
    int u = blockIdx.x;            // 1024
    int tid = threadIdx.x;         // 256
    float4 x = reinterpret_cast<const float4*>(W_w + (size_t)u * 2 * H_DIM)[tid];
    uint2 p;
    p.x = f2bf(x.x) | (f2bf(x.y) << 16);
    p.y = f2bf(x.z) | (f2bf(x.w) << 16);
    reinterpret_cast<uint2*>(wv)[(size_t)u * (H_DIM / 4) + tid] = p;
}

// ---------- pass 0b: c[b][u] = q[b] . Wq[u] + W_b[u]  (fp32 exact) + zero ctx ----------
// grid (16, 8), 256 threads; each block serves 4 batches from LDS-staged q.
__global__ void prep_c_kernel(const float* __restrict__ q,     // [B][H]
                              const float* __restrict__ W_w,   // [U][2H]
                              const float* __restrict__ W_b,   // [U]
                              float* __restrict__ cvec,        // [B][U]
                              float* __restrict__ ctx) {       // [B][H] -> zeroed here
    __shared__ float4 q_sh[4][H_DIM / 4];     // 16 KB
    int bg = blockIdx.y;           // batch group: batches bg*4 .. bg*4+3
    int u0 = blockIdx.x * 64;
    int tid = threadIdx.x;
    int lane = tid & 63, w = tid >> 6;
    // zero ctx: 128 blocks x 256 threads = 32768 = B*H exactly
    ctx[(size_t)(blockIdx.y * 16 + blockIdx.x) * 256 + tid] = 0.f;
#pragma unroll
    for (int i = 0; i < 4; i++)
        q_sh[i][tid] = reinterpret_cast<const float4*>(
            q + (size_t)(bg * 4 + i) * H_DIM)[tid];
    __syncthreads();
#pragma unroll
    for (int i = 0; i < 16; i++) {
        int u = u0 + w * 16 + i;
        const float4* wr = reinterpret_cast<const float4*>(W_w + (size_t)u * 2 * H_DIM + H_DIM);
        float s0 = 0.f, s1 = 0.f, s2 = 0.f, s3 = 0.f;
#pragma unroll
        for (int j = 0; j < 4; j++) {
            float4 wv4 = wr[j * 64 + lane];
            float4 qa = q_sh[0][j * 64 + lane];
            float4 qb = q_sh[1][j * 64 + lane];
            float4 qc = q_sh[2][j * 64 + lane];
            float4 qd = q_sh[3][j * 64 + lane];
            s0 += wv4.x * qa.x + wv4.y * qa.y + wv4.z * qa.z + wv4.w * qa.w;
            s1 += wv4.x * qb.x + wv4.y * qb.y + wv4.z * qb.z + wv4.w * qb.w;
            s2 += wv4.x * qc.x + wv4.y * qc.y + wv4.z * qc.z + wv4.w * qc.w;
            s3 += wv4.x * qd.x + wv4.y * qd.y + wv4.z * qd.z + wv4.w * qd.w;
        }
#pragma unroll
        for (int off = 32; off >= 1; off >>= 1) {
            s0 += __shfl_xor(s0, off, 64);
            s1 += __shfl_xor(s1, off, 64);
            s2 += __shfl_xor(s2, off, 64);
            s3 += __shfl_xor(s3, off, 64);
        }
        if (lane == 0) {
            float bb = W_b[u];
            cvec[(size_t)(bg * 4 + 0) * U_DIM + u] = s0 + bb;
            cvec[(size_t)(bg * 4 + 1) * U_DIM + u] = s1 + bb;
            cvec[(size_t)(bg * 4 + 2) * U_DIM + u] = s2 + bb;
            cvec[(size_t)(bg * 4 + 3) * U_DIM + u] = s3 + bb;
        }
    }
}

// ---------- pass 1: GEMM(values, Wv^T) + tanh + dot(V_w) -> partial score ----------
// 256(M) x 256(N) tile, BK=64, 8 waves (2x4), wave tile 128x64, acc[8][4].
// A (values, fp32->bf16) and B (wv) both LDS-staged with XOR swizzle
// ((row&7)<<3 on short index) -> conflict-free ds_read_b128 (T2).
// N split over 4 blocks -> partial scores to score_part[4][B*T] (no atomics).
// XCD-chunked swizzle: 4 n-siblings of an m-tile on one XCD share A in L2 (T1).
__global__ __launch_bounds__(512, 2)
void gemm_score_kernel(const float* __restrict__ values,        // [B*T][H]
                       const unsigned short* __restrict__ wv,   // bf16 [U][H]
                       const float* __restrict__ cvec,          // [B][U]
                       const float* __restrict__ Vw,            // [U]
                       float* __restrict__ score_part) {        // [4][B*T]
    __shared__ __align__(16) unsigned short a_sh[2][256 * 64];  // 64 KB
    __shared__ __align__(16) unsigned short b_sh[2][256 * 64];  // 64 KB

    const int tid = threadIdx.x;
    const int lane = tid & 63;
    const int w = tid >> 6;          // wave 0..7
    const int col = lane & 15;
    const int quad = lane >> 4;
    const int wr = w >> 2;           // 0..1 (M half)
    const int wc = w & 3;            // 0..3 (N quarter)

    // XCD-chunked bijective swizzle (1024 % 8 == 0)
    const int work = (blockIdx.x & 7) * 128 + (blockIdx.x >> 3);
    const int mtile = work >> 2;     // 0..255
    const int ntile = work & 3;      // 0..3
    const int m0 = mtile * 256;
    const int b = m0 >> 11;

    f32x4 acc[8][4];
    const f32x4 zero4 = {0.f, 0.f, 0.f, 0.f};
#pragma unroll
    for (int mt = 0; mt < 8; mt++)
#pragma unroll
        for (int nt = 0; nt < 4; nt++) acc[mt][nt] = zero4;

    const float4* v4 = reinterpret_cast<const float4*>(values);
    const uint4* wv4 = reinterpret_cast<const uint4*>(wv);

    // A staging map: per thread k16 = tid&15 (float4 within K-slice),
    // rows rb+32j (rb = tid>>4, j<8). LDS short idx = row*64 + ((k16*4)^((row&7)<<3)).
    const int arb = tid >> 4;
    const int ak16 = tid & 15;
    const int asw = (arb & 7) << 3;          // row&7 invariant under +32j
    // B staging map: n = tid>>1, kh = tid&1, j<4 (uint4 each).
    const int bn = tid >> 1;
    const int bkh = tid & 1;
    const int bsw = (bn & 7) << 3;

    // prologue: stage tile 0 into buf 0
    {
        uint4 bstg[4];
        const uint4* bgl = wv4 + (size_t)(ntile * 256 + bn) * 128 + bkh * 4;
#pragma unroll
        for (int j = 0; j < 4; j++) bstg[j] = bgl[j];
        float4 astg[8];
        const float4* agl = v4 + (size_t)(m0 + arb) * 256 + ak16;
#pragma unroll
        for (int j = 0; j < 8; j++) astg[j] = agl[(size_t)8192 * j];
#pragma unroll
        for (int j = 0; j < 4; j++)
            *reinterpret_cast<uint4*>(&b_sh[0][bn * 64 + ((bkh * 32 + j * 8) ^ bsw)]) = bstg[j];
#pragma unroll
        for (int j = 0; j < 8; j++) {
            uint2 p;
            p.x = f2bf(astg[j].x) | (f2bf(astg[j].y) << 16);
            p.y = f2bf(astg[j].z) | (f2bf(astg[j].w) << 16);
            *reinterpret_cast<uint2*>(&a_sh[0][(arb + 32 * j) * 64 + ((ak16 * 4) ^ asw)]) = p;
        }
    }
    __syncthreads();

    const int swz = (col & 7) << 3;  // fragment-read swizzle (row&7 == col&7)

    for (int ks = 0; ks < 16; ks++) {
        const int cur = ks & 1;

        // issue next-tile loads first (hidden under this tile's MFMAs)
        uint4 bstg[4];
        float4 astg[8];
        if (ks < 15) {
            const uint4* bgl = wv4 + (size_t)(ntile * 256 + bn) * 128 + (ks + 1) * 8 + bkh * 4;
#pragma unroll
            for (int j = 0; j < 4; j++) bstg[j] = bgl[j];
            const float4* agl = v4 + (size_t)(m0 + arb) * 256 + (ks + 1) * 16 + ak16;
#pragma unroll
            for (int j = 0; j < 8; j++) astg[j] = agl[(size_t)8192 * j];
        }
        // pin VMEM issue point (loads may not sink below; everything else free)
        __builtin_amdgcn_sched_barrier(0x38F);

#pragma unroll
        for (int kk = 0; kk < 2; kk++) {
            bf16x8 af[8];
            bf16x8 bf[4];
#pragma unroll
            for (int mt = 0; mt < 8; mt++)
                af[mt] = *reinterpret_cast<const bf16x8*>(
                    &a_sh[cur][(wr * 128 + mt * 16 + col) * 64 + ((kk * 32 + quad * 8) ^ swz)]);
#pragma unroll
            for (int nt = 0; nt < 4; nt++)
                bf[nt] = *reinterpret_cast<const bf16x8*>(
                    &b_sh[cur][(wc * 64 + nt * 16 + col) * 64 + ((kk * 32 + quad * 8) ^ swz)]);
#pragma unroll
            for (int nt = 0; nt < 4; nt++)
#pragma unroll
                for (int mt = 0; mt < 8; mt++)
                    acc[mt][nt] = __builtin_amdgcn_mfma_f32_16x16x32_bf16(
                        af[mt], bf[nt], acc[mt][nt], 0, 0, 0);
            // retire B staging early (B is L2-resident; frees regs before kk=1)
            if (kk == 0 && ks < 15) {
#pragma unroll
                for (int j = 0; j < 4; j++)
                    *reinterpret_cast<uint4*>(
                        &b_sh[1 - cur][bn * 64 + ((bkh * 32 + j * 8) ^ bsw)]) = bstg[j];
            }
        }

        if (ks < 15) {
#pragma unroll
            for (int j = 0; j < 8; j++) {
                uint2 p;
                p.x = f2bf(astg[j].x) | (f2bf(astg[j].y) << 16);
                p.y = f2bf(astg[j].z) | (f2bf(astg[j].w) << 16);
                *reinterpret_cast<uint2*>(
                    &a_sh[1 - cur][(arb + 32 * j) * 64 + ((ak16 * 4) ^ asw)]) = p;
            }
        }
        __syncthreads();
    }

    // ---- epilogue: partial score over this block's 256 u-cols ----
    float* sc = reinterpret_cast<float*>(a_sh);   // reuse LDS (all reads drained)
    float cv[4], vwv[4];
#pragma unroll
    for (int nt = 0; nt < 4; nt++) {
        int n = ntile * 256 + wc * 64 + nt * 16 + col;
        cv[nt] = cvec[(size_t)b * U_DIM + n];
        vwv[nt] = Vw[n];
    }
#pragma unroll
    for (int mt = 0; mt < 8; mt++) {
#pragma unroll
        for (int j = 0; j < 4; j++) {
            float s = 0.f;
#pragma unroll
            for (int nt = 0; nt < 4; nt++)
                s += fast_tanh(acc[mt][nt][j] + cv[nt]) * vwv[nt];
            s += __shfl_xor(s, 1, 64);
            s += __shfl_xor(s, 2, 64);
            s += __shfl_xor(s, 4, 64);
            s += __shfl_xor(s, 8, 64);
            if (col == 0) sc[(wr * 128 + mt * 16 + quad * 4 + j) * 4 + wc] = s;
        }
    }
    __syncthreads();
    if (tid < 256) {
        float s = sc[tid * 4] + sc[tid * 4 + 1] + sc[tid * 4 + 2] + sc[tid * 4 + 3];
        score_part[(size_t)ntile * (B_DIM * T_DIM) + m0 + tid] = s;
    }
}

// ---------- pass 2: fused softmax + context partial + atomic combine ----------
// grid (16, 32), 256 threads. Each block recomputes the (cheap) softmax stats
// for its batch, writes its 128-t chunk of aw, and atomically accumulates its
// partial context into ctx (zeroed by prep_c).
__global__ void ctx_sm_kernel(const float* __restrict__ values,
                              const float* __restrict__ score_part,  // [4][B*T]
                              float* __restrict__ aw,                // [B][T]
                              float* __restrict__ ctx) {             // [B][H]
    int tc = blockIdx.x;           // 16 chunks of 128 t
    int b = blockIdx.y;            // 32
    int tid = threadIdx.x;         // 256
    int lane = tid & 63, w = tid >> 6;
    __shared__ float redm[4];
    __shared__ float reds[4];
    __shared__ float aw_sh[128];
    const float* sp = score_part + (size_t)b * T_DIM;
    float loc[8];
    float m = -1e30f;
#pragma unroll
    for (int i = 0; i < 8; i++) {
        int t = tid + i * 256;
        float s = sp[t] + sp[65536 + t] + sp[131072 + t] + sp[196608 + t];
        loc[i] = s;
        m = fmaxf(m, s);
    }
#pragma unroll
    for (int off = 32; off >= 1; off >>= 1) m = fmaxf(m, __shfl_xor(m, off, 64));
    if (lane == 0) redm[w] = m;
    __syncthreads();
    m = fmaxf(fmaxf(redm[0], redm[1]), fmaxf(redm[2], redm[3]));
    float sum = 0.f;
#pragma unroll
    for (int i = 0; i < 8; i++) {
        loc[i] = __expf(loc[i] - m);
        sum += loc[i];
    }
#pragma unroll
    for (int off = 32; off >= 1; off >>= 1) sum += __shfl_xor(sum, off, 64);
    if (lane == 0) reds[w] = sum;
    __syncthreads();
    sum = reds[0] + reds[1] + reds[2] + reds[3];
    float inv = 1.0f / sum;
    // write this block's 128-t chunk of aw + stash for the ctx pass
    if (tid < 128) {
        int t = tc * 128 + tid;
        float s = sp[t] + sp[65536 + t] + sp[131072 + t] + sp[196608 + t];
        float av = __expf(s - m) * inv;
        aw[(size_t)b * T_DIM + t] = av;
        aw_sh[tid] = av;
    }
    __syncthreads();
    const float4* v4 = reinterpret_cast<const float4*>(
                           values + ((size_t)b * T_DIM + tc * 128) * H_DIM) + tid;
    float4 a = make_float4(0.f, 0.f, 0.f, 0.f);
#pragma unroll 4
    for (int t = 0; t < 128; t++) {
        float wgt = aw_sh[t];
        float4 vv = v4[(size_t)t * (H_DIM / 4)];
        a.x += wgt * vv.x; a.y += wgt * vv.y;
        a.z += wgt * vv.z; a.w += wgt * vv.w;
    }
    float* cp = ctx + (size_t)b * H_DIM + tid * 4;
    atomicAdd(cp + 0, a.x);
    atomicAdd(cp + 1, a.y);
    atomicAdd(cp + 2, a.z);
    atomicAdd(cp + 3, a.w);
}

extern "C" void kernel_launch(void* const* d_in, const int* in_sizes, int n_in,
                              void* d_out, int out_size, void* d_ws, size_t ws_size,
                              hipStream_t stream) {
    const float* query  = (const float*)d_in[0];   // [1][B][H]
    const float* values = (const float*)d_in[1];   // [B][T][H]
    const float* W_w    = (const float*)d_in[2];   // [U][2H]
    const float* W_b    = (const float*)d_in[3];   // [U]
    const float* V_w    = (const float*)d_in[4];   // [1][U]
    // d_in[5] = V_b: uniform score shift, cancels in softmax -> unused.

    float* out = (float*)d_out;
    char* ws = (char*)d_ws;
    float* cvec            = (float*)(ws);                               // 128 KB
    unsigned short* wv     = (unsigned short*)(ws + 131072);             // 2 MB
    float* score_part      = (float*)(ws + 131072 + 2097152);            // 1 MB
    float* ctx = out;                    // [B][H]
    float* aw  = out + B_DIM * H_DIM;    // [B][T]

    prep_wv_kernel<<<U_DIM, 256, 0, stream>>>(W_w, wv);
    prep_c_kernel<<<dim3(U_DIM / 64, B_DIM / 4), 256, 0, stream>>>(query, W_w, W_b, cvec, ctx);
    gemm_score_kernel<<<1024, 512, 0, stream>>>(values, wv, cvec, V_w, score_part);
    ctx_sm_kernel<<<dim3(16, B_DIM), 256, 0, stream>>>(values, score_part, aw, ctx);
}

// Round 3
// 594.258 us; speedup vs baseline: 1.2972x; 1.2972x over previous
//
#include <hip/hip_runtime.h>
#include <hip/hip_bf16.h>

// Shapes (fixed by reference): B=32, T=2048, H=1024, U=1024.
// out = [context (32*1024)][attention_weights (32*2048)]  (fp32)
// V_b is a uniform score shift -> cancels in softmax -> unused.

#define B_DIM 32
#define T_DIM 2048
#define H_DIM 1024
#define U_DIM 1024

typedef __bf16 bf16x8 __attribute__((ext_vector_type(8)));
typedef float f32x4 __attribute__((ext_vector_type(4)));

__device__ __forceinline__ unsigned int f2bf(float f) {
    unsigned int u = __float_as_uint(f);
    return (u + 0x7FFFu + ((u >> 16) & 1u)) >> 16;   // RNE
}

__device__ __forceinline__ unsigned int cvt2(float lo, float hi) {
    unsigned int r;
    asm volatile("v_cvt_pk_bf16_f32 %0, %1, %2" : "=v"(r) : "v"(lo), "v"(hi));
    return r;   // RNE packed pair, low half = lo
}

__device__ __forceinline__ float fast_tanh(float x) {
    x = fminf(9.f, fmaxf(-9.f, x));
    float e = __expf(2.f * x);
    return 1.f - 2.f * __frcp_rn(e + 1.f);
}

__device__ __forceinline__ void glds16(const void* g, void* l) {
    __builtin_amdgcn_global_load_lds(
        (const __attribute__((address_space(1))) unsigned int*)g,
        (__attribute__((address_space(3))) unsigned int*)l, 16, 0, 0);
}

// ---------- pass 0a: Wv (first H cols of W_w rows) -> bf16, natural [u][k] ----------
__global__ void prep_wv_kernel(const float* __restrict__ W_w,
                               unsigned short* __restrict__ wv) {
    int u = blockIdx.x;            // 1024
    int tid = threadIdx.x;         // 256
    float4 x = reinterpret_cast<const float4*>(W_w + (size_t)u * 2 * H_DIM)[tid];
    uint2 p;
    p.x = f2bf(x.x) | (f2bf(x.y) << 16);
    p.y = f2bf(x.z) | (f2bf(x.w) << 16);
    reinterpret_cast<uint2*>(wv)[(size_t)u * (H_DIM / 4) + tid] = p;
}

// ---------- pass 0b: c[b][u] = q[b] . Wq[u] + W_b[u]  (fp32 exact) + zero ctx ----------
__global__ void prep_c_kernel(const float* __restrict__ q,     // [B][H]
                              const float* __restrict__ W_w,   // [U][2H]
                              const float* __restrict__ W_b,   // [U]
                              float* __restrict__ cvec,        // [B][U]
                              float* __restrict__ ctx) {       // [B][H] -> zeroed here
    __shared__ float4 q_sh[4][H_DIM / 4];     // 16 KB
    int bg = blockIdx.y;           // batch group: batches bg*4 .. bg*4+3
    int u0 = blockIdx.x * 64;
    int tid = threadIdx.x;
    int lane = tid & 63, w = tid >> 6;
    ctx[(size_t)(blockIdx.y * 16 + blockIdx.x) * 256 + tid] = 0.f;
#pragma unroll
    for (int i = 0; i < 4; i++)
        q_sh[i][tid] = reinterpret_cast<const float4*>(
            q + (size_t)(bg * 4 + i) * H_DIM)[tid];
    __syncthreads();
#pragma unroll
    for (int i = 0; i < 16; i++) {
        int u = u0 + w * 16 + i;
        const float4* wr = reinterpret_cast<const float4*>(W_w + (size_t)u * 2 * H_DIM + H_DIM);
        float s0 = 0.f, s1 = 0.f, s2 = 0.f, s3 = 0.f;
#pragma unroll
        for (int j = 0; j < 4; j++) {
            float4 wv4 = wr[j * 64 + lane];
            float4 qa = q_sh[0][j * 64 + lane];
            float4 qb = q_sh[1][j * 64 + lane];
            float4 qc = q_sh[2][j * 64 + lane];
            float4 qd = q_sh[3][j * 64 + lane];
            s0 += wv4.x * qa.x + wv4.y * qa.y + wv4.z * qa.z + wv4.w * qa.w;
            s1 += wv4.x * qb.x + wv4.y * qb.y + wv4.z * qb.z + wv4.w * qb.w;
            s2 += wv4.x * qc.x + wv4.y * qc.y + wv4.z * qc.z + wv4.w * qc.w;
            s3 += wv4.x * qd.x + wv4.y * qd.y + wv4.z * qd.z + wv4.w * qd.w;
        }
#pragma unroll
        for (int off = 32; off >= 1; off >>= 1) {
            s0 += __shfl_xor(s0, off, 64);
            s1 += __shfl_xor(s1, off, 64);
            s2 += __shfl_xor(s2, off, 64);
            s3 += __shfl_xor(s3, off, 64);
        }
        if (lane == 0) {
            float bb = W_b[u];
            cvec[(size_t)(bg * 4 + 0) * U_DIM + u] = s0 + bb;
            cvec[(size_t)(bg * 4 + 1) * U_DIM + u] = s1 + bb;
            cvec[(size_t)(bg * 4 + 2) * U_DIM + u] = s2 + bb;
            cvec[(size_t)(bg * 4 + 3) * U_DIM + u] = s3 + bb;
        }
    }
}

// ---------- pass 1: GEMM(values, Wv^T) + tanh + dot(V_w) -> partial score ----------
// 256(M) x 256(N) tile, BK=32, 32 K-steps, 8 waves (2x4), wave tile 128x64.
// DEPTH-2 PIPELINE, raw s_barrier, counted vmcnt(6) -- never drained to 0 in
// the main loop (T3+T4). 4 LDS buffers (mod-4 rotation keeps every concurrent
// read/write pair disjoint; single barrier per K-step).
//   B (bf16 wv):   global_load_lds direct, source pre-swizzled (slot ^= n&3).
//   A (fp32 vals): reg-staged float4 ping-pong (issue at t for t+2; cvt_pk ->
//                  ds_write at t+1), slot ^= row&3 on write and read.
__global__ __launch_bounds__(512, 2)
void gemm_score_kernel(const float* __restrict__ values,        // [B*T][H]
                       const unsigned short* __restrict__ wv,   // bf16 [U][H]
                       const float* __restrict__ cvec,          // [B][U]
                       const float* __restrict__ Vw,            // [U]
                       float* __restrict__ score_part) {        // [4][B*T]
    __shared__ __align__(16) unsigned short a_sh[4][256 * 32];  // 64 KB
    __shared__ __align__(16) unsigned short b_sh[4][256 * 32];  // 64 KB

    const int tid = threadIdx.x;
    const int lane = tid & 63;
    const int w = tid >> 6;          // wave 0..7
    const int col = lane & 15;
    const int quad = lane >> 4;
    const int wr = w >> 2;           // 0..1 (M half)
    const int wc = w & 3;            // 0..3 (N quarter)

    // XCD-chunked bijective swizzle (1024 % 8 == 0)
    const int work = (blockIdx.x & 7) * 128 + (blockIdx.x >> 3);
    const int mtile = work >> 2;     // 0..255
    const int ntile = work & 3;      // 0..3
    const int m0 = mtile * 256;
    const int b = m0 >> 11;

    f32x4 acc[8][4];
    const f32x4 zero4 = {0.f, 0.f, 0.f, 0.f};
#pragma unroll
    for (int mt = 0; mt < 8; mt++)
#pragma unroll
        for (int nt = 0; nt < 4; nt++) acc[mt][nt] = zero4;

    // A staging map: row = tid>>1, khalf = tid&1 (16 floats/thread/step)
    const int arow = tid >> 1;
    const int akh = tid & 1;
    const float4* agl = reinterpret_cast<const float4*>(values) +
                        ((size_t)(m0 + arow) * 256 + akh * 4);
    const int as0 = (akh * 2) ^ (arow & 3);   // swizzled 16B-slot for first write

    // B glds source (pre-swizzled): wave w stages rows [ntile*256+w*32, +32)
    const int bn0 = ntile * 256 + w * 32 + (lane >> 2);
    const int bslot = ((lane & 3) ^ ((lane >> 2) & 3)) * 16;
    const char* bsrc0 = (const char*)wv + (size_t)bn0 * 2048 + bslot;
    const char* bsrc1 = bsrc0 + 16 * 2048;

    // fragment read offsets (shorts), slot ^= (row&3) == (col&3)
    const int fro = (quad ^ (col & 3)) * 8;
    const int aro = (wr * 128 + col) * 32 + fro;
    const int bro = (wc * 64 + col) * 32 + fro;

#define AISSUE(SET, TS) do {                                                   \
        SET[0] = agl[(TS) * 8 + 0]; SET[1] = agl[(TS) * 8 + 1];                \
        SET[2] = agl[(TS) * 8 + 2]; SET[3] = agl[(TS) * 8 + 3];                \
    } while (0)

#define BISSUE(TS) do {                                                        \
        glds16(bsrc0 + (size_t)(TS) * 64, &b_sh[(TS) & 3][w * 1024]);          \
        glds16(bsrc1 + (size_t)(TS) * 64, &b_sh[(TS) & 3][w * 1024 + 512]);    \
    } while (0)

#define AWRITE(SET, TS) do {                                                   \
        uint4 p0, p1;                                                          \
        p0.x = cvt2(SET[0].x, SET[0].y); p0.y = cvt2(SET[0].z, SET[0].w);      \
        p0.z = cvt2(SET[1].x, SET[1].y); p0.w = cvt2(SET[1].z, SET[1].w);      \
        p1.x = cvt2(SET[2].x, SET[2].y); p1.y = cvt2(SET[2].z, SET[2].w);      \
        p1.z = cvt2(SET[3].x, SET[3].y); p1.w = cvt2(SET[3].z, SET[3].w);      \
        *reinterpret_cast<uint4*>(&a_sh[(TS) & 3][arow * 32 + as0 * 8]) = p0;  \
        *reinterpret_cast<uint4*>(&a_sh[(TS) & 3][arow * 32 + (as0 ^ 1) * 8]) = p1; \
    } while (0)

#define KSTEP_CORE(T) do {                                                     \
        const int cb_ = (T) & 3;                                               \
        bf16x8 af[8], bf[4];                                                   \
        _Pragma("unroll")                                                      \
        for (int mt = 0; mt < 8; mt++)                                         \
            af[mt] = *reinterpret_cast<const bf16x8*>(&a_sh[cb_][aro + mt * 512]); \
        _Pragma("unroll")                                                      \
        for (int nt = 0; nt < 4; nt++)                                         \
            bf[nt] = *reinterpret_cast<const bf16x8*>(&b_sh[cb_][bro + nt * 512]); \
        __builtin_amdgcn_s_setprio(1);                                         \
        _Pragma("unroll")                                                      \
        for (int nt = 0; nt < 4; nt++)                                         \
            _Pragma("unroll")                                                  \
            for (int mt = 0; mt < 8; mt++)                                     \
                acc[mt][nt] = __builtin_amdgcn_mfma_f32_16x16x32_bf16(         \
                    af[mt], bf[nt], acc[mt][nt], 0, 0, 0);                     \
        __builtin_amdgcn_s_setprio(0);                                         \
    } while (0)

    float4 sA[4], sB[4];   // A(even) -> sA, A(odd) -> sB; static indexing only

    // prologue: tiles 0 and 1 in flight; write A(0)
    AISSUE(sA, 0); BISSUE(0);
    AISSUE(sB, 1); BISSUE(1);
    AWRITE(sA, 0);                       // compiler auto-waits sA's loads

    for (int tt = 0; tt < 30; tt += 2) {
        // ---- step tt (even): issue t+2, write A(t+1), compute t ----
        AISSUE(sA, tt + 2); BISSUE(tt + 2);
        asm volatile("s_waitcnt vmcnt(6)" ::: "memory");  // tile tt fully landed
        AWRITE(sB, tt + 1);
        asm volatile("s_waitcnt lgkmcnt(0)" ::: "memory");
        __builtin_amdgcn_s_barrier();
        asm volatile("" ::: "memory");
        KSTEP_CORE(tt);
        // ---- step tt+1 (odd) ----
        AISSUE(sB, tt + 3); BISSUE(tt + 3);
        asm volatile("s_waitcnt vmcnt(6)" ::: "memory");
        AWRITE(sA, tt + 2);
        asm volatile("s_waitcnt lgkmcnt(0)" ::: "memory");
        __builtin_amdgcn_s_barrier();
        asm volatile("" ::: "memory");
        KSTEP_CORE(tt + 1);
    }
    // ---- step 30: no issue; write A(31) ----
    AWRITE(sB, 31);                      // compiler auto-waits sB's loads
    asm volatile("s_waitcnt lgkmcnt(0)" ::: "memory");
    __builtin_amdgcn_s_barrier();
    asm volatile("" ::: "memory");
    KSTEP_CORE(30);
    // ---- step 31: drain remaining glds, compute last tile ----
    asm volatile("s_waitcnt vmcnt(0)" ::: "memory");
    __builtin_amdgcn_s_barrier();
    asm volatile("" ::: "memory");
    KSTEP_CORE(31);

    __syncthreads();

#undef AISSUE
#undef BISSUE
#undef AWRITE
#undef KSTEP_CORE

    // ---- epilogue: partial score over this block's 256 u-cols ----
    float* sc = reinterpret_cast<float*>(a_sh);   // reuse LDS
    float cv[4], vwv[4];
#pragma unroll
    for (int nt = 0; nt < 4; nt++) {
        int n = ntile * 256 + wc * 64 + nt * 16 + col;
        cv[nt] = cvec[(size_t)b * U_DIM + n];
        vwv[nt] = Vw[n];
    }
#pragma unroll
    for (int mt = 0; mt < 8; mt++) {
#pragma unroll
        for (int j = 0; j < 4; j++) {
            float s = 0.f;
#pragma unroll
            for (int nt = 0; nt < 4; nt++)
                s += fast_tanh(acc[mt][nt][j] + cv[nt]) * vwv[nt];
            s += __shfl_xor(s, 1, 64);
            s += __shfl_xor(s, 2, 64);
            s += __shfl_xor(s, 4, 64);
            s += __shfl_xor(s, 8, 64);
            if (col == 0) sc[(wr * 128 + mt * 16 + quad * 4 + j) * 4 + wc] = s;
        }
    }
    __syncthreads();
    if (tid < 256) {
        float s = sc[tid * 4] + sc[tid * 4 + 1] + sc[tid * 4 + 2] + sc[tid * 4 + 3];
        score_part[(size_t)ntile * (B_DIM * T_DIM) + m0 + tid] = s;
    }
}

// ---------- pass 2: fused softmax + context partial + atomic combine ----------
__global__ void ctx_sm_kernel(const float* __restrict__ values,
                              const float* __restrict__ score_part,  // [4][B*T]
                              float* __restrict__ aw,                // [B][T]
                              float* __restrict__ ctx) {             // [B][H]
    int tc = blockIdx.x;           // 16 chunks of 128 t
    int b = blockIdx.y;            // 32
    int tid = threadIdx.x;         // 256
    int lane = tid & 63, w = tid >> 6;
    __shared__ float redm[4];
    __shared__ float reds[4];
    __shared__ float aw_sh[128];
    const float* sp = score_part + (size_t)b * T_DIM;
    float loc[8];
    float m = -1e30f;
#pragma unroll
    for (int i = 0; i < 8; i++) {
        int t = tid + i * 256;
        float s = sp[t] + sp[65536 + t] + sp[131072 + t] + sp[196608 + t];
        loc[i] = s;
        m = fmaxf(m, s);
    }
#pragma unroll
    for (int off = 32; off >= 1; off >>= 1) m = fmaxf(m, __shfl_xor(m, off, 64));
    if (lane == 0) redm[w] = m;
    __syncthreads();
    m = fmaxf(fmaxf(redm[0], redm[1]), fmaxf(redm[2], redm[3]));
    float sum = 0.f;
#pragma unroll
    for (int i = 0; i < 8; i++) {
        loc[i] = __expf(loc[i] - m);
        sum += loc[i];
    }
#pragma unroll
    for (int off = 32; off >= 1; off >>= 1) sum += __shfl_xor(sum, off, 64);
    if (lane == 0) reds[w] = sum;
    __syncthreads();
    sum = reds[0] + reds[1] + reds[2] + reds[3];
    float inv = 1.0f / sum;
    if (tid < 128) {
        int t = tc * 128 + tid;
        float s = sp[t] + sp[65536 + t] + sp[131072 + t] + sp[196608 + t];
        float av = __expf(s - m) * inv;
        aw[(size_t)b * T_DIM + t] = av;
        aw_sh[tid] = av;
    }
    __syncthreads();
    const float4* v4 = reinterpret_cast<const float4*>(
                           values + ((size_t)b * T_DIM + tc * 128) * H_DIM) + tid;
    float4 a = make_float4(0.f, 0.f, 0.f, 0.f);
#pragma unroll 4
    for (int t = 0; t < 128; t++) {
        float wgt = aw_sh[t];
        float4 vv = v4[(size_t)t * (H_DIM / 4)];
        a.x += wgt * vv.x; a.y += wgt * vv.y;
        a.z += wgt * vv.z; a.w += wgt * vv.w;
    }
    float* cp = ctx + (size_t)b * H_DIM + tid * 4;
    atomicAdd(cp + 0, a.x);
    atomicAdd(cp + 1, a.y);
    atomicAdd(cp + 2, a.z);
    atomicAdd(cp + 3, a.w);
}

extern "C" void kernel_launch(void* const* d_in, const int* in_sizes, int n_in,
                              void* d_out, int out_size, void* d_ws, size_t ws_size,
                              hipStream_t stream) {
    const float* query  = (const float*)d_in[0];   // [1][B][H]
    const float* values = (const float*)d_in[1];   // [B][T][H]
    const float* W_w    = (const float*)d_in[2];   // [U][2H]
    const float* W_b    = (const float*)d_in[3];   // [U]
    const float* V_w    = (const float*)d_in[4];   // [1][U]
    // d_in[5] = V_b: uniform score shift, cancels in softmax -> unused.

    float* out = (float*)d_out;
    char* ws = (char*)d_ws;
    float* cvec            = (float*)(ws);                               // 128 KB
    unsigned short* wv     = (unsigned short*)(ws + 131072);             // 2 MB
    float* score_part      = (float*)(ws + 131072 + 2097152);            // 1 MB
    float* ctx = out;                    // [B][H]
    float* aw  = out + B_DIM * H_DIM;    // [B][T]

    prep_wv_kernel<<<U_DIM, 256, 0, stream>>>(W_w, wv);
    prep_c_kernel<<<dim3(U_DIM / 64, B_DIM / 4), 256, 0, stream>>>(query, W_w, W_b, cvec, ctx);
    gemm_score_kernel<<<1024, 512, 0, stream>>>(values, wv, cvec, V_w, score_part);
    ctx_sm_kernel<<<dim3(16, B_DIM), 256, 0, stream>>>(values, score_part, aw, ctx);
}